// Round 2
// 293.897 us; speedup vs baseline: 1.0433x; 1.0433x over previous
//
#include <hip/hip_runtime.h>
#include <hip/hip_bf16.h>

// MetaNetImageEncoder on MI355X — round 5 (resubmit; r5 bench was an infra
// failure: "MI355X container failed twice" — no kernel verdict, no counters).
// Post-mortem r4: k_gemm_pool (2x91.5us = 60% of total) is latency-bound:
// MfmaUtil 8.2%, HBM 7.6%, occupancy 31.7%. Cause: un-pipelined 2-phase
// K-loop (stage -> __syncthreads drains vmcnt(0) -> MFMA) — full global-load
// latency on the critical path every k-iter.
// r5 changes (k_gemm_pool only):
//  - Double-buffered LDS + 1-deep pipelined schedule (guide T3-minimal):
//    issue stage(k+1) BEFORE ds_read+MFMA(k); single __syncthreads per iter.
//  - MIX B-path uses T14 async-STAGE split: raw BF8 global loads issued
//    before compute (held in 72 VGPR), mix VALU + ds_write AFTER the MFMAs
//    (avoids lgkm in-order chaining of load latency in front of MFMA).
//  - Staged A rows trimmed 256->224 (rows >=196 are zero pad; wave 3 computes
//    only mf<2). LDS = 2*28KB(A) + 2*8KB(B) = 72KB -> 2 blocks/CU with slack.
//  - __launch_bounds__(256,2): 256-VGPR cap so the held wreg[2][9] fits
//    without the scratch spill that killed r3.
//
// MFMA 16x16x32 bf16 layouts (learn_hip m89):
//   A-frag: A[m=lane&15][k=(lane>>4)*8+j], B-frag: B[k=(lane>>4)*8+j][n=lane&15]
//   C/D:    col=lane&15, row=(lane>>4)*4+reg

typedef __bf16 bf16x8 __attribute__((ext_vector_type(8)));
typedef float f32x4 __attribute__((ext_vector_type(4)));
typedef __hip_bfloat16 bf16;

struct alignas(16) BF8 { bf16 h[8]; };

constexpr int BATCH = 64;
constexpr int NP    = 196;
constexpr int NPAD  = 256;
constexpr int DIM   = 768;
constexpr int NT    = 8;
constexpr size_t MSZ = (size_t)DIM * DIM;

__device__ __forceinline__ void async_cp16(const void* g, void* l) {
  __builtin_amdgcn_global_load_lds(
      (const __attribute__((address_space(1))) uint32_t*)g,
      (__attribute__((address_space(3))) uint32_t*)l, 16, 0, 0);
}

// ---------------- K1: patchify + cast to bf16, pad rows to 256 ----------------
__global__ void k_patchify(const float* __restrict__ x, bf16* __restrict__ A) {
  int idx  = blockIdx.x * blockDim.x + threadIdx.x;
  int col4 = idx % (DIM / 4);
  int row  = idx / (DIM / 4);
  int d = col4 * 4;
  int b = row >> 8;
  int n = row & 255;
  bf16 tmp[4];
  if (n < NP) {
    int hp = n / 14, wp = n % 14;
    int c  = d >> 8;
    int rr = d & 255;
    int i = rr >> 4, j = rr & 15;
    const float* src = x + ((((size_t)b * 3 + c) * 224 + hp * 16 + i) * 224 + wp * 16 + j);
    float4 f = *(const float4*)src;
    tmp[0] = __float2bfloat16(f.x);
    tmp[1] = __float2bfloat16(f.y);
    tmp[2] = __float2bfloat16(f.z);
    tmp[3] = __float2bfloat16(f.w);
  } else {
    tmp[0] = tmp[1] = tmp[2] = tmp[3] = __float2bfloat16(0.0f);
  }
  *(ushort4*)(A + (size_t)row * DIM + d) = *(ushort4*)tmp;
}

// ---------------- K2: transpose + cast weights: WT[mat][n][k] = W[mat][k][n] ----------------
__global__ void k_transpose_cast(const float* __restrict__ W1, const float* __restrict__ dW1,
                                 const float* __restrict__ W2, const float* __restrict__ dW2,
                                 bf16* __restrict__ WT) {
  __shared__ float tile[32][33];
  int mat = blockIdx.z;
  const float* src;
  if      (mat == 0) src = W1;
  else if (mat <= 8) src = dW1 + (size_t)(mat - 1) * MSZ;
  else if (mat == 9) src = W2;
  else               src = dW2 + (size_t)(mat - 10) * MSZ;
  int n0 = blockIdx.x * 32;
  int k0 = blockIdx.y * 32;
  int tx = threadIdx.x & 31, ty = threadIdx.x >> 5;
#pragma unroll
  for (int r = ty; r < 32; r += 8)
    tile[r][tx] = src[(size_t)(k0 + r) * DIM + n0 + tx];
  __syncthreads();
  bf16* dst = WT + (size_t)mat * MSZ;
#pragma unroll
  for (int r = ty; r < 32; r += 8)
    dst[(size_t)(n0 + r) * DIM + k0 + tx] = __float2bfloat16(tile[tx][r]);
}

// ---------------- K3: per-sample GEMM (+inline mix) + relu + masked column-mean --------------
// grid (64 samples, 12 n-tiles) = 768 blocks. BM=224 staged (rows>=196 are
// zero pad; wave 3 computes only mf<2), BN=64, BK=64. Double-buffered LDS,
// 1-deep pipelined: stage(k+1) issued before MFMA(k); one barrier per iter.
// LDS XOR-swizzled granules: slot(r,c) = r*8 + (c ^ (r&7)); swizzle folded
// into the per-lane GLOBAL source address (global_load_lds dst is lane-linear).

template<int MIX>
__global__ __launch_bounds__(256, 2)
void k_gemm_pool(const bf16* __restrict__ A,    // [64*256, 768]
                 const bf16* __restrict__ WT,   // mats 0..8 = W1T, dW1T[8]
                 const float* __restrict__ b1,
                 const float* __restrict__ db1,
                 const float* __restrict__ coefs,  // [64][8] (MIX only)
                 float* __restrict__ pooled) {     // f32 [64][768]
  __shared__ uint4 AslU[2][1792];   // 224 rows x 8 granules, x2 buffers (56KB)
  __shared__ uint4 BslU[2][512];    //  64 rows x 8 granules, x2 buffers (16KB)

  int b  = blockIdx.x;
  int n0 = blockIdx.y * 64;
  int tid = threadIdx.x;
  int wave = tid >> 6, lane = tid & 63;
  int quad = lane >> 4, l16 = lane & 15;

  float cr[NT];
  if (MIX) {
#pragma unroll
    for (int t = 0; t < NT; t++) cr[t] = coefs[b * NT + t];
  }

  const bf16* Ag = A + (size_t)b * NPAD * DIM;
  f32x4 acc[4][4] = {};

  // ---- A stage: 1792 granules = 28 wave-instrs, 7 per wave, async to LDS
  auto stage_a = [&](int buf, int kt) {
    const bf16* Ak = Ag + kt * 64;
#pragma unroll
    for (int i = 0; i < 7; i++) {
      int s = (wave * 7 + i) * 64 + lane;
      int r = s >> 3, c = (s & 7) ^ (r & 7);
      async_cp16(Ak + (size_t)r * DIM + c * 8, (void*)&AslU[buf][(wave * 7 + i) * 64]);
    }
  };
  // ---- B stage, phase A: async, 2 instrs per wave
  auto stage_b_async = [&](int buf, int kt) {
    const bf16* Wk = WT + kt * 64;
#pragma unroll
    for (int i = 0; i < 2; i++) {
      int s = (wave * 2 + i) * 64 + lane;
      int r = s >> 3, c = (s & 7) ^ (r & 7);
      async_cp16(Wk + (size_t)(n0 + r) * DIM + c * 8, (void*)&BslU[buf][(wave * 2 + i) * 64]);
    }
  };
  // ---- B stage, phase B (T14 split): load raw tiles early ...
  BF8 wreg[2][9];   // 2 granules x (W1 + 8 deltas), 72 VGPR in flight
  auto mixb_load = [&](int kt) {
    const bf16* Wk = WT + kt * 64;
#pragma unroll
    for (int i = 0; i < 2; i++) {
      int g = tid + 256 * i;
      int r = g >> 3, c = (g & 7) ^ (r & 7);
      const bf16* p0 = Wk + (size_t)(n0 + r) * DIM + c * 8;
      wreg[i][0] = *(const BF8*)p0;
#pragma unroll
      for (int t = 0; t < NT; t++)
        wreg[i][1 + t] = *(const BF8*)(p0 + (size_t)(1 + t) * MSZ);
    }
  };
  // ... mix + ds_write late (after the MFMAs, before the barrier)
  auto mixb_write = [&](int buf) {
#pragma unroll
    for (int i = 0; i < 2; i++) {
      int g = tid + 256 * i;
      float m[8];
#pragma unroll
      for (int j = 0; j < 8; j++) m[j] = __bfloat162float(wreg[i][0].h[j]);
#pragma unroll
      for (int t = 0; t < NT; t++) {
        float cc = cr[t];
#pragma unroll
        for (int j = 0; j < 8; j++) m[j] += cc * __bfloat162float(wreg[i][1 + t].h[j]);
      }
      BF8 o;
#pragma unroll
      for (int j = 0; j < 8; j++) o.h[j] = __float2bfloat16(m[j]);
      BslU[buf][g] = *(uint4*)&o;
    }
  };

  // ---- prologue: fill buffer 0
  stage_a(0, 0);
  if (MIX) { mixb_load(0); mixb_write(0); }
  else     stage_b_async(0, 0);
  __syncthreads();

  // ---- pipelined K-loop
  int cur = 0;
  for (int kt = 0; kt < 12; kt++) {
    if (kt < 11) {
      stage_a(cur ^ 1, kt + 1);
      if (MIX) mixb_load(kt + 1);
      else     stage_b_async(cur ^ 1, kt + 1);
    }
    const bf16* As = (const bf16*)AslU[cur];
    const bf16* Bs = (const bf16*)BslU[cur];
#pragma unroll
    for (int ks = 0; ks < 2; ks++) {
      bf16x8 bfr[4];
#pragma unroll
      for (int nf = 0; nf < 4; nf++) {
        int brow = nf * 16 + l16;
        bfr[nf] = *(const bf16x8*)(Bs + ((size_t)brow * 8 + ((ks * 4 + quad) ^ (brow & 7))) * 8);
      }
#pragma unroll
      for (int mf = 0; mf < 4; mf++) {
        if (wave * 64 + mf * 16 < 224) {   // wave-uniform; wave 3 does mf<2
          int arow = wave * 64 + mf * 16 + l16;
          bf16x8 af = *(const bf16x8*)(As + ((size_t)arow * 8 + ((ks * 4 + quad) ^ (arow & 7))) * 8);
#pragma unroll
          for (int nf = 0; nf < 4; nf++)
            acc[mf][nf] = __builtin_amdgcn_mfma_f32_16x16x32_bf16(af, bfr[nf], acc[mf][nf], 0, 0, 0);
        }
      }
    }
    if (MIX && kt < 11) mixb_write(cur ^ 1);
    __syncthreads();   // drains vmcnt (stage issued a full compute-phase ago)
    cur ^= 1;
  }

  // ---- epilogue: relu(acc + bias), mask pad rows, column sums
  float* red = (float*)&BslU[0][0];   // LDS reuse after final barrier
  int m0 = wave * 64;
  float colsum[4];
#pragma unroll
  for (int nf = 0; nf < 4; nf++) {
    int col = n0 + nf * 16 + l16;
    float bias = b1[col];
    if (MIX) {
#pragma unroll
      for (int t = 0; t < NT; t++) bias += cr[t] * db1[t * DIM + col];
    }
    float s = 0.0f;
#pragma unroll
    for (int mf = 0; mf < 4; mf++) {
      int rbase = m0 + mf * 16 + quad * 4;
#pragma unroll
      for (int r = 0; r < 4; r++) {
        if (rbase + r < NP) s += fmaxf(acc[mf][nf][r] + bias, 0.0f);
      }
    }
    s += __shfl_xor(s, 16, 64);
    s += __shfl_xor(s, 32, 64);
    colsum[nf] = s;
  }
  if (lane < 16) {
#pragma unroll
    for (int nf = 0; nf < 4; nf++) red[wave * 64 + nf * 16 + lane] = colsum[nf];
  }
  __syncthreads();
  if (tid < 64) {
    float s = red[tid] + red[64 + tid] + red[128 + tid] + red[192 + tid];
    pooled[(size_t)b * DIM + n0 + tid] = s * (1.0f / 196.0f);
  }
}

// ---------------- K5: small GEMM, M=64: Y[mat] = Af(f32->bf16) @ WT[matbase+mat] ------------
__global__ __launch_bounds__(256, 2)
void k_gemm2(const float* __restrict__ Af,    // [64][768] f32
             const bf16* __restrict__ WT,
             int matbase,
             const float* __restrict__ bias,  // [768] or null
             float* __restrict__ Y) {         // [nmat][64][768]
  __shared__ uint4 AslU[64 * 8];
  __shared__ uint4 BslU[64 * 8];
  int n0  = blockIdx.x * 64;
  int mat = blockIdx.y;
  int tid = threadIdx.x, wave = tid >> 6, lane = tid & 63;
  int quad = lane >> 4, l16 = lane & 15;
  f32x4 acc[4] = {};
  const bf16* Wm = WT + (size_t)(matbase + mat) * MSZ;
  for (int k0 = 0; k0 < DIM; k0 += 64) {
#pragma unroll
    for (int i = 0; i < 2; i++) {
      int g = tid + i * 256;
      int r = g >> 3, c = g & 7;
      const float* src = Af + (size_t)r * DIM + k0 + c * 8;
      float4 xa = ((const float4*)src)[0];
      float4 xb = ((const float4*)src)[1];
      BF8 o;
      o.h[0] = __float2bfloat16(xa.x); o.h[1] = __float2bfloat16(xa.y);
      o.h[2] = __float2bfloat16(xa.z); o.h[3] = __float2bfloat16(xa.w);
      o.h[4] = __float2bfloat16(xb.x); o.h[5] = __float2bfloat16(xb.y);
      o.h[6] = __float2bfloat16(xb.z); o.h[7] = __float2bfloat16(xb.w);
      AslU[r * 8 + (c ^ (r & 7))] = *(uint4*)&o;
      BslU[r * 8 + (c ^ (r & 7))] = *(const uint4*)(Wm + (size_t)(n0 + r) * DIM + k0 + c * 8);
    }
    __syncthreads();
    const bf16* As = (const bf16*)AslU;
    const bf16* Bs = (const bf16*)BslU;
#pragma unroll
    for (int ks = 0; ks < 2; ks++) {
      int brow = wave * 16 + l16;
      bf16x8 bfr = *(const bf16x8*)(Bs + (size_t)(brow * 8 + ((ks * 4 + quad) ^ (brow & 7))) * 8);
#pragma unroll
      for (int mf = 0; mf < 4; mf++) {
        int arow = mf * 16 + l16;
        bf16x8 af = *(const bf16x8*)(As + (size_t)(arow * 8 + ((ks * 4 + quad) ^ (arow & 7))) * 8);
        acc[mf] = __builtin_amdgcn_mfma_f32_16x16x32_bf16(af, bfr, acc[mf], 0, 0, 0);
      }
    }
    __syncthreads();
  }
#pragma unroll
  for (int mf = 0; mf < 4; mf++) {
#pragma unroll
    for (int r = 0; r < 4; r++) {
      int row = mf * 16 + quad * 4 + r;
      int col = n0 + wave * 16 + l16;
      float v = acc[mf][r];
      if (bias) v += bias[col];
      Y[((size_t)mat * 64 + row) * DIM + col] = v;
    }
  }
}

// ---------------- K6: MetaNet: coefs = relu(base@mw1+mb1)@mw2 + mb2 ----------------
__global__ void k_metanet(const float* __restrict__ base,  // [64][768]
                          const float* __restrict__ mw1, const float* __restrict__ mb1,
                          const float* __restrict__ mw2, const float* __restrict__ mb2,
                          float* __restrict__ coefs) {     // [64][8]
  __shared__ float bl[DIM];
  __shared__ float hl[192];
  int b = blockIdx.x, tid = threadIdx.x;   // 192 threads
  for (int i = tid; i < DIM; i += 192) bl[i] = base[(size_t)b * DIM + i];
  __syncthreads();
  float s = mb1[tid];
  for (int k = 0; k < DIM; k++) s += bl[k] * mw1[(size_t)k * 192 + tid];
  hl[tid] = fmaxf(s, 0.0f);
  __syncthreads();
  if (tid < NT) {
    float c = mb2[tid];
    for (int j = 0; j < 192; j++) c += hl[j] * mw2[(size_t)j * NT + tid];
    coefs[b * NT + tid] = c;
  }
}

// ---------------- K7: combine: out = Y0 + b2 + sum_t c_t (Y[1+t] + db2_t) ----------------
__global__ void k_combine(const float* __restrict__ Y,
                          const float* __restrict__ coefs,
                          const float* __restrict__ b2,
                          const float* __restrict__ db2,
                          float* __restrict__ out) {
  int idx = blockIdx.x * 256 + threadIdx.x;
  int b = idx / DIM, e = idx % DIM;
  float v = Y[(size_t)b * DIM + e] + b2[e];
#pragma unroll
  for (int t = 0; t < NT; t++) {
    float c = coefs[b * NT + t];
    v += c * (Y[((size_t)(1 + t) * 64 + b) * DIM + e] + db2[(size_t)t * DIM + e]);
  }
  out[idx] = v;
}

extern "C" void kernel_launch(void* const* d_in, const int* in_sizes, int n_in,
                              void* d_out, int out_size, void* d_ws, size_t ws_size,
                              hipStream_t stream) {
  const float* x   = (const float*)d_in[0];
  const float* W1  = (const float*)d_in[1];
  const float* b1  = (const float*)d_in[2];
  const float* W2  = (const float*)d_in[3];
  const float* b2  = (const float*)d_in[4];
  const float* dW1 = (const float*)d_in[5];
  const float* db1 = (const float*)d_in[6];
  const float* dW2 = (const float*)d_in[7];
  const float* db2 = (const float*)d_in[8];
  const float* mw1 = (const float*)d_in[9];
  const float* mb1 = (const float*)d_in[10];
  const float* mw2 = (const float*)d_in[11];
  const float* mb2 = (const float*)d_in[12];
  float* out = (float*)d_out;
  (void)in_sizes; (void)n_in; (void)out_size; (void)ws_size;

  // workspace layout (bytes) — total ~48.8 MB
  char* ws = (char*)d_ws;
  bf16*  A_bf    = (bf16*) (ws);                 // 25,165,824
  bf16*  WT      = (bf16*) (ws + 25165824);      // 21,233,664 -> 46,399,488
  float* pooledA = (float*)(ws + 46399488);      //    196,608 -> 46,596,096
  float* pooledB = (float*)(ws + 46596096);      //    196,608 -> 46,792,704
  float* coefs   = (float*)(ws + 46792704);      //      2,048 -> 46,794,752
  float* base    = (float*)(ws + 46794752);      //    196,608 -> 46,991,360
  float* Y       = (float*)(ws + 46991360);      //  1,769,472 -> 48,760,832

  k_patchify<<<dim3((BATCH * NPAD * (DIM / 4)) / 256), 256, 0, stream>>>(x, A_bf);
  k_transpose_cast<<<dim3(24, 24, 18), 256, 0, stream>>>(W1, dW1, W2, dW2, WT);
  // phase A
  k_gemm_pool<0><<<dim3(BATCH, DIM / 64), 256, 0, stream>>>(A_bf, WT, b1, db1, nullptr, pooledA);
  k_gemm2<<<dim3(DIM / 64, 1), 256, 0, stream>>>(pooledA, WT, 9, b2, base);
  k_metanet<<<dim3(BATCH), 192, 0, stream>>>(base, mw1, mb1, mw2, mb2, coefs);
  // phase B (inline mix from L2-resident WT)
  k_gemm_pool<1><<<dim3(BATCH, DIM / 64), 256, 0, stream>>>(A_bf, WT, b1, db1, coefs, pooledB);
  k_gemm2<<<dim3(DIM / 64, 9), 256, 0, stream>>>(pooledB, WT, 9, nullptr, Y);
  k_combine<<<dim3((BATCH * DIM) / 256), 256, 0, stream>>>(Y, coefs, b2, db2, out);
}